// Round 3
// baseline (695.329 us; speedup 1.0000x reference)
//
#include <hip/hip_runtime.h>
#include <hip/hip_bf16.h>
#include <float.h>
#include <cstdint>

// ---------------------------------------------------------------------------
// RCSLS: out = ( topk10sum(X_trans@Z_tgt^T)/10 + topk10sum(Y_tgt@Z_trans^T)/10
//               - 2*sum(X_trans*Y_tgt) ) / 4096
// B=4096, N=32768, d=512, k=10.  Inputs f32; GEMMs in bf16 MFMA.
//
// R7 (= R6 resubmit + sched_barrier hardening): 256x256 tile, 8 waves
// (2M x 4N), MFMA 32x32x16.  K pipelined as 16 sub-tiles of K=32 through a
// 4-slot (4 x 32KB = 128KB) LDS rotation.  BOTH operand fragment sets are
// register-double-buffered at half-KSTEP (K=16) granularity, so no MFMA
// cluster waits on a same-KSTEP ds_read.  ONE barrier per KSTEP (14 total):
// VMCNT(4) before it publishes S(J+2); STAGE(J+4) after it overwrites the
// just-retired slot.  sched_barrier(0) pins each MFMA cluster (and its
// operand lgkmcnt waits) before the slot-recycling barrier (WAR safety).
//
// Pipeline ledger (per wave, 4 gloads per sub-tile):
//   prologue: STAGE S0..S3 (16 loads), vmcnt(8) [S0,S1 landed], barrier,
//             load frags (0,kk0)
//   KSTEP J:  load frags (J,kk1) | MFMA (J,kk0) | load frags (J+1,kk0)
//             | MFMA (J,kk1)
//             J<12 : vmcnt(4) [S(J+2) landed; S(J+3) in flight], barrier,
//                    STAGE(J+4) -> slot J&3
//             J=12 : vmcnt(4) [S14 landed], barrier
//             J=13 : vmcnt(0) [S15 landed], barrier
//             J=14,15: no barrier needed (no more stages)
// Swapped MFMA operands (mfma(b_frag, a_frag)): lane&31 = X-row, so the
// per-(row, 64-col-window) top-4 runs in registers: packed-u16 insertion
// network + ONE shfl_xor(32) bitonic merge.  P layout & merge kernel
// unchanged; sortable-u16 mapping bit-identical to previous versions.
// ---------------------------------------------------------------------------

#define B_ROWS 4096
#define N_COLS 32768
#define D_K    512
#define NCHUNK (N_COLS / 128)   // 256 chunks of 128 cols (P layout, unchanged)

typedef __bf16 bf16x8 __attribute__((ext_vector_type(8)));
typedef float  f32x16 __attribute__((ext_vector_type(16)));
typedef unsigned short u16x2 __attribute__((ext_vector_type(2)));

__device__ __forceinline__ unsigned short f2bf(float f) {
    unsigned int u = __float_as_uint(f);
    u += 0x7FFFu + ((u >> 16) & 1u);   // RNE
    return (unsigned short)(u >> 16);
}
// monotone map: f32 order == unsigned order of (f2sort32(f)>>16).
__device__ __forceinline__ unsigned f2sort32(float f) {
    unsigned u = __float_as_uint(f);
    u += 0x7FFFu + ((u >> 16) & 1u);               // RNE to bf16 in high half
    return u ^ (0x80000000u | (unsigned)((int)u >> 31));
}
__device__ __forceinline__ float sort2f(unsigned int y) {
    unsigned int x = (y & 0x8000u) ? (y ^ 0x8000u) : (~y & 0xFFFFu);
    return __uint_as_float(x << 16);
}
__device__ __forceinline__ unsigned umax(unsigned a, unsigned b) { return a > b ? a : b; }
__device__ __forceinline__ unsigned umin(unsigned a, unsigned b) { return a < b ? a : b; }

__device__ __forceinline__ void gload_lds16(const void* g, void* l) {
    __builtin_amdgcn_global_load_lds(
        (const __attribute__((address_space(1))) unsigned int*)(uintptr_t)g,
        (__attribute__((address_space(3))) unsigned int*)(uintptr_t)l,
        16, 0, 0);
}

// ---- zero the 3 scalar accumulators -----------------------------------------
__global__ void zero_scalars(float* sc) {
    if (threadIdx.x < 3) sc[threadIdx.x] = 0.0f;
}

// ---- fused f32->bf16 conversion (4 arrays) + dot(X,Y); grid.y selects ------
__global__ void prep_kernel(const float4* __restrict__ X,
                            const float4* __restrict__ Y,
                            const float4* __restrict__ Zt,
                            const float4* __restrict__ Ztr,
                            ushort4* __restrict__ A0, ushort4* __restrict__ A1,
                            ushort4* __restrict__ B0, ushort4* __restrict__ B1,
                            float* __restrict__ dotacc) {
    const int z = blockIdx.y;
    int i = blockIdx.x * 256 + threadIdx.x;
    const int stride = gridDim.x * 256;
    if (z == 0) {
        float s = 0.0f;
        for (; i < B_ROWS * D_K / 4; i += stride) {
            float4 x = X[i], y = Y[i];
            ushort4 u; u.x = f2bf(x.x); u.y = f2bf(x.y);
            u.z = f2bf(x.z); u.w = f2bf(x.w);
            A0[i] = u;
            s += x.x * y.x + x.y * y.y + x.z * y.z + x.w * y.w;
        }
        for (int o = 32; o > 0; o >>= 1) s += __shfl_down(s, o);
        __shared__ float wsum[4];
        int lane = threadIdx.x & 63, w = threadIdx.x >> 6;
        if (lane == 0) wsum[w] = s;
        __syncthreads();
        if (threadIdx.x == 0)
            atomicAdd(dotacc, wsum[0] + wsum[1] + wsum[2] + wsum[3]);
    } else {
        const float4* src = (z == 1) ? Y : (z == 2) ? Zt : Ztr;
        ushort4* dst = (z == 1) ? A1 : (z == 2) ? B0 : B1;
        int n4 = (z == 1) ? (B_ROWS * D_K / 4) : (N_COLS * D_K / 4);
        for (; i < n4; i += stride) {
            float4 f = src[i];
            ushort4 u; u.x = f2bf(f.x); u.y = f2bf(f.y);
            u.z = f2bf(f.z); u.w = f2bf(f.w);
            dst[i] = u;
        }
    }
}

// ---- pipeline / epilogue macros --------------------------------------------
#define BARRIER()  asm volatile("s_barrier" ::: "memory")
#define VMCNT(N)   asm volatile("s_waitcnt vmcnt(" #N ")" ::: "memory")
#define SCHEDB()   __builtin_amdgcn_sched_barrier(0)

// stage sub-tile T (K cols [T*32, T*32+32)) into slot T&3.
// wave w stages A rows [w*32, w*32+32) and B cols likewise; lane order ==
// fragment order (conflict-free by construction; LDS dest is wave-uniform).
#define STAGE(T) do { \
    gload_lds16(gA + (T) * 32,      smem + ((T) & 3) * 16384 + (w * 2 + 0) * 512); \
    gload_lds16(gA + (T) * 32 + 16, smem + ((T) & 3) * 16384 + (w * 2 + 1) * 512); \
    gload_lds16(gB + (T) * 32,      smem + ((T) & 3) * 16384 + 8192 + (w * 2 + 0) * 512); \
    gload_lds16(gB + (T) * 32 + 16, smem + ((T) & 3) * 16384 + 8192 + (w * 2 + 1) * 512); \
} while (0)

// load one half-KSTEP's fragments (4 A frags + 2 B frags) from slot/kk
#define LOADH(AF, BF, SLOT, KK) { \
    _Pragma("unroll") for (int rb = 0; rb < 4; ++rb) \
        AF[rb] = *(const bf16x8*)(smem + (SLOT) * 16384 + ((wm * 4 + rb) * 2 + (KK)) * 512 + lane8); \
    _Pragma("unroll") for (int cb = 0; cb < 2; ++cb) \
        BF[cb] = *(const bf16x8*)(smem + (SLOT) * 16384 + 8192 + ((wn * 2 + cb) * 2 + (KK)) * 512 + lane8); \
}

// 8 MFMAs: acc[rb][cb] += BF[cb] (M=cols) x AF[rb] (N=rows)
#define MFMAH(AF, BF) { __builtin_amdgcn_s_setprio(1); \
    _Pragma("unroll") for (int rb = 0; rb < 4; ++rb) { \
    _Pragma("unroll") for (int cb = 0; cb < 2; ++cb) { \
        acc[rb][cb] = __builtin_amdgcn_mfma_f32_32x32x16_bf16( \
            BF[cb], AF[rb], acc[rb][cb], 0, 0, 0); } } \
    __builtin_amdgcn_s_setprio(0); }

#define KSTEP(J) do { \
    LOADH(afn, bfn, (J) & 3, 1); \
    SCHEDB(); \
    MFMAH(afc, bfc); \
    if ((J) < 15) LOADH(afc, bfc, ((J) + 1) & 3, 0); \
    SCHEDB(); \
    MFMAH(afn, bfn); \
    SCHEDB(); \
    if ((J) < 12)       { VMCNT(4); BARRIER(); STAGE((J) + 4); } \
    else if ((J) == 12) { VMCNT(4); BARRIER(); } \
    else if ((J) == 13) { VMCNT(0); BARRIER(); } \
} while (0)

#define CSWAP(a, b) { unsigned _hi = umax(a, b), _lo = umin(a, b); a = _hi; b = _lo; }
#define SORT4() { CSWAP(m0, m1); CSWAP(m2, m3); CSWAP(m0, m2); CSWAP(m1, m3); CSWAP(m1, m2); }
#define INS(V) { u16x2 _hi; \
    _hi = __builtin_elementwise_max(t0, V); V = __builtin_elementwise_min(t0, V); t0 = _hi; \
    _hi = __builtin_elementwise_max(t1, V); V = __builtin_elementwise_min(t1, V); t1 = _hi; \
    _hi = __builtin_elementwise_max(t2, V); V = __builtin_elementwise_min(t2, V); t2 = _hi; \
    _hi = __builtin_elementwise_max(t3, V); V = __builtin_elementwise_min(t3, V); t3 = _hi; }

// ---- 256x256 bf16 GEMM (32x32x16 MFMA) + in-register per-(row,64col) top-4 -
// grid (2048, 2): y selects which GEMM. 512 threads = 8 waves (2M x 4N).
__global__ __launch_bounds__(512, 2)
void gemm_topk_kernel(const unsigned short* __restrict__ A0g,
                      const unsigned short* __restrict__ A1g,
                      const unsigned short* __restrict__ B0g,
                      const unsigned short* __restrict__ B1g,
                      uint2* __restrict__ P0, uint2* __restrict__ P1) {
    const unsigned short* A  = blockIdx.y ? A1g : A0g;
    const unsigned short* Bm = blockIdx.y ? B1g : B0g;
    uint2* P2 = blockIdx.y ? P1 : P0;

    __shared__ __align__(128) unsigned short smem[4 * 16384];  // 128 KiB

    const int tid   = threadIdx.x;
    const int lane  = tid & 63;
    const int w     = tid >> 6;       // wave 0..7
    const int wm    = w >> 2;         // 0..1 : 128-row half
    const int wn    = w & 3;          // 0..3 : 64-col window
    const int rlane = lane & 31;
    const int hi    = lane >> 5;
    const int lane8 = lane * 8;

    // XCD swizzle: xcd owns a 16-col-block window; 8-block group stays in L2
    const int b      = blockIdx.x;
    const int xcd    = b & 7;
    const int ii     = b >> 3;            // 0..255
    const int cw     = ii & 7;
    const int rowblk = (ii >> 3) & 15;
    const int cg     = ii >> 7;           // 0..1
    const int bn     = xcd * 16 + cg * 8 + cw;   // 0..127
    const int row0   = rowblk * 256;
    const int col0   = bn * 256;

    // staging sources: wave w owns A block row0+w*32.., B block col0+w*32..;
    // lane (hi,rlane) -> row +rlane, k-offset hi*8  (fragment lane order)
    const unsigned short* gA = A  + (size_t)(row0 + w * 32 + rlane) * D_K + hi * 8;
    const unsigned short* gB = Bm + (size_t)(col0 + w * 32 + rlane) * D_K + hi * 8;

    f32x16 acc[4][2];
    #pragma unroll
    for (int rb = 0; rb < 4; ++rb)
        #pragma unroll
        for (int cb = 0; cb < 2; ++cb)
            #pragma unroll
            for (int e = 0; e < 16; ++e)
                acc[rb][cb][e] = 0.0f;

    bf16x8 afc[4], afn[4], bfc[2], bfn[2];

    // ---- prologue ----
    STAGE(0);
    STAGE(1);
    STAGE(2);
    STAGE(3);
    VMCNT(8);        // S0, S1 landed (per wave)
    BARRIER();       // publish S0, S1
    LOADH(afc, bfc, 0, 0)

    // ---- main loop: 16 K sub-tiles ----
    KSTEP(0);  KSTEP(1);  KSTEP(2);  KSTEP(3);
    KSTEP(4);  KSTEP(5);  KSTEP(6);  KSTEP(7);
    KSTEP(8);  KSTEP(9);  KSTEP(10); KSTEP(11);
    KSTEP(12); KSTEP(13); KSTEP(14); KSTEP(15);

    // ---- epilogue: per-row top-4 of this wave's 64-col window, in regs ----
    // 32x32 swapped C layout: X-row = rlane (fixed/lane); col-within-block =
    // (reg&3) + 8*(reg>>2) + 4*hi.  Lane holds 16 cols of each of the 2
    // col-blocks = 32 of the window's 64; partner lane^32 holds the rest.
    const int chunk = bn * 2 + (wn >> 1);
    const int half  = wn & 1;
    #pragma unroll
    for (int rb = 0; rb < 4; ++rb) {
        u16x2 t0 = {0, 0}, t1 = {0, 0}, t2 = {0, 0}, t3 = {0, 0};
        #pragma unroll
        for (int cb = 0; cb < 2; ++cb) {
            #pragma unroll
            for (int p = 0; p < 8; ++p) {
                unsigned sa = f2sort32(acc[rb][cb][2 * p]);
                unsigned sb = f2sort32(acc[rb][cb][2 * p + 1]);
                unsigned pk = (sa >> 16) | (sb & 0xFFFF0000u);
                u16x2 v = *(u16x2*)&pk;
                INS(v);
            }
        }
        // top-4 multiset of this lane's 32 values (chains sorted desc)
        unsigned m0 = umax((unsigned)t0.x, (unsigned)t3.y);
        unsigned m1 = umax((unsigned)t1.x, (unsigned)t2.y);
        unsigned m2 = umax((unsigned)t2.x, (unsigned)t1.y);
        unsigned m3 = umax((unsigned)t3.x, (unsigned)t0.y);
        SORT4();
        // single bitonic merge with lane^32 (partner holds the other 32 cols)
        {
            unsigned pa = m0 | (m1 << 16);
            unsigned pb = m2 | (m3 << 16);
            unsigned qa = (unsigned)__shfl_xor((int)pa, 32);
            unsigned qb = (unsigned)__shfl_xor((int)pb, 32);
            unsigned ra = (qa >> 16) | (qa << 16);   // (q1, q0)
            unsigned rb2 = (qb >> 16) | (qb << 16);  // (q3, q2)
            u16x2 n0 = __builtin_elementwise_max(*(u16x2*)&pa, *(u16x2*)&rb2);
            u16x2 n1 = __builtin_elementwise_max(*(u16x2*)&pb, *(u16x2*)&ra);
            m0 = n0.x; m1 = n0.y; m2 = n1.x; m3 = n1.y;
            SORT4();
        }
        if (hi == 0) {
            int row_g = row0 + wm * 128 + rb * 32 + rlane;
            P2[((size_t)row_g * NCHUNK + chunk) * 2 + half] =
                make_uint2(m0 | (m1 << 16), m2 | (m3 << 16));
        }
    }
}

// ---- per-row exact top-10 over 2048 u16 candidates; one wave per row --------
// grid (1024, 2): y selects which GEMM's P / accumulator.  (unchanged)
__global__ __launch_bounds__(256, 4)
void merge_topk_kernel(const unsigned int* __restrict__ P0,
                       const unsigned int* __restrict__ P1,
                       float* __restrict__ sc) {
    const int g    = blockIdx.y;
    const int lane = threadIdx.x & 63;
    const int w    = threadIdx.x >> 6;
    const int row  = blockIdx.x * 4 + w;
    const unsigned int* Rp = (g ? P1 : P0) + (size_t)row * (NCHUNK * 4); // 1024 u32

    u16x2 t[10];
    #pragma unroll
    for (int i = 0; i < 10; ++i) t[i] = (u16x2){0, 0};
    #pragma unroll 4
    for (int it = 0; it < 16; ++it) {
        unsigned int raw = Rp[lane + 64 * it];
        u16x2 v = *(u16x2*)&raw;
        #pragma unroll
        for (int i = 0; i < 10; ++i) {
            u16x2 hi = __builtin_elementwise_max(t[i], v);
            v = __builtin_elementwise_min(t[i], v);
            t[i] = hi;
        }
    }
    unsigned int wreg[10];
    #pragma unroll
    for (int i = 0; i < 10; ++i) {
        unsigned int mv = umax((unsigned int)t[i].x,
                               (unsigned int)t[9 - i].y);
        wreg[i] = (mv << 16) | ((unsigned int)lane << 4) | (unsigned int)i;
    }
    float sum10 = 0.0f;
    #pragma unroll
    for (int iter = 0; iter < 10; ++iter) {
        unsigned int mx = wreg[0];
        #pragma unroll
        for (int s = 1; s < 10; ++s) mx = umax(mx, wreg[s]);
        #pragma unroll
        for (int o = 32; o > 0; o >>= 1)
            mx = umax(mx, (unsigned int)__shfl_xor((int)mx, o));
        sum10 += sort2f(mx >> 16);
        #pragma unroll
        for (int s = 0; s < 10; ++s)
            if (wreg[s] == mx) wreg[s] = 0u;
    }
    if (lane == 0) atomicAdd(sc + 1 + g, sum10);
}

// ---- final scalar -----------------------------------------------------------
__global__ void finalize_kernel(const float* __restrict__ sc,
                                float* __restrict__ out) {
    if (threadIdx.x == 0) {
        float f = (sc[1] * 0.1f + sc[2] * 0.1f - 2.0f * sc[0]) * (1.0f / 4096.0f);
        out[0] = f;
    }
}

extern "C" void kernel_launch(void* const* d_in, const int* in_sizes, int n_in,
                              void* d_out, int out_size, void* d_ws, size_t ws_size,
                              hipStream_t stream) {
    const float* X_trans = (const float*)d_in[1];
    const float* Y_tgt   = (const float*)d_in[2];
    const float* Z_trans = (const float*)d_in[4];
    const float* Z_tgt   = (const float*)d_in[5];

    char* ws = (char*)d_ws;
    float* sc = (float*)ws;                                  // [0]=dot [1]=fk0 [2]=fk1
    unsigned short* A0 = (unsigned short*)(ws + 256);        // X_trans bf16 [4096,512]
    unsigned short* A1 = A0 + (size_t)B_ROWS * D_K;          // Y_tgt  bf16
    unsigned short* B0 = A1 + (size_t)B_ROWS * D_K;          // Z_tgt  bf16 [32768,512]
    unsigned short* B1 = B0 + (size_t)N_COLS * D_K;          // Z_trans bf16
    uint2* P0 = (uint2*)(B1 + (size_t)N_COLS * D_K);         // [4096][256][2] uint2
    uint2* P1 = P0 + (size_t)B_ROWS * NCHUNK * 2;

    zero_scalars<<<1, 64, 0, stream>>>(sc);

    dim3 pgrid(2048, 4);
    prep_kernel<<<pgrid, 256, 0, stream>>>(
        (const float4*)X_trans, (const float4*)Y_tgt,
        (const float4*)Z_tgt, (const float4*)Z_trans,
        (ushort4*)A0, (ushort4*)A1, (ushort4*)B0, (ushort4*)B1, sc + 0);

    dim3 ggrid(2048, 2);
    gemm_topk_kernel<<<ggrid, 512, 0, stream>>>(A0, A1, B0, B1, P0, P1);

    dim3 mgrid(B_ROWS / 4, 2);
    merge_topk_kernel<<<mgrid, 256, 0, stream>>>(
        (const unsigned int*)P0, (const unsigned int*)P1, sc);

    finalize_kernel<<<1, 64, 0, stream>>>(sc, (float*)d_out);
}

// Round 4
// 692.392 us; speedup vs baseline: 1.0042x; 1.0042x over previous
//
#include <hip/hip_runtime.h>
#include <hip/hip_bf16.h>
#include <float.h>
#include <cstdint>

// ---------------------------------------------------------------------------
// RCSLS: out = ( topk10sum(X_trans@Z_tgt^T)/10 + topk10sum(Y_tgt@Z_trans^T)/10
//               - 2*sum(X_trans*Y_tgt) ) / 4096
// B=4096, N=32768, d=512, k=10.  Inputs f32; GEMMs in bf16 MFMA.
//
// R8 = R7 minus the self-inflicted scheduling fences.
// 256x256 tile, 8 waves (2M x 4N), MFMA 32x32x16, 16 K sub-tiles of 32
// through a 4-slot (4 x 32KB = 128KB) LDS rotation, register-double-buffered
// fragments at half-KSTEP granularity, ONE barrier per KSTEP.
//
// R7 post-mortem: sched_barrier(0) between LOADH and MFMAH (plus setprio's
// motion-barrier effect) forced strict read-phase / MFMA-phase alternation:
// LDS port idle during MFMA, matrix pipe idle during reads -> phases ADD
// (~3.4k cyc/KSTEP vs ~1.1k overlapped).  This is the documented m141
// failure mode.  Fix: no sched_barrier, no setprio; the compiler interleaves
// ds_reads among MFMAs with fine-grained lgkmcnt(N) waits (m97-verified).
// WAR safety (slot J reads complete before STAGE(J+4) overwrites slot J&3)
// now comes from an explicit lgkmcnt(0) drain before the recycling barrier.
//
// Pipeline ledger (per wave, 4 gloads per sub-tile):
//   prologue: STAGE S0..S3 (16 loads), vmcnt(8) [S0,S1 landed], barrier,
//             load frags (0,kk0)
//   KSTEP J:  load frags (J,kk1) | MFMA (J,kk0) | load frags (J+1,kk0)
//             | MFMA (J,kk1)     (compiler free to interleave all of these)
//             J<12 : lgkmcnt(0) [all my slot reads sampled], vmcnt(4)
//                    [S(J+2) landed], barrier, STAGE(J+4) -> slot J&3
//             J=12 : vmcnt(4) [S14 landed], barrier
//             J=13 : vmcnt(0) [S15 landed], barrier
//             J=14,15: no barrier needed (no more stages)
// Swapped MFMA operands (mfma(b_frag, a_frag)): lane&31 = X-row, so the
// per-(row, 64-col-window) top-4 runs in registers: packed-u16 insertion
// network + ONE shfl_xor(32) bitonic merge.  P layout & merge kernel
// unchanged; sortable-u16 mapping bit-identical to previous versions.
// ---------------------------------------------------------------------------

#define B_ROWS 4096
#define N_COLS 32768
#define D_K    512
#define NCHUNK (N_COLS / 128)   // 256 chunks of 128 cols (P layout, unchanged)

typedef __bf16 bf16x8 __attribute__((ext_vector_type(8)));
typedef float  f32x16 __attribute__((ext_vector_type(16)));
typedef unsigned short u16x2 __attribute__((ext_vector_type(2)));

__device__ __forceinline__ unsigned short f2bf(float f) {
    unsigned int u = __float_as_uint(f);
    u += 0x7FFFu + ((u >> 16) & 1u);   // RNE
    return (unsigned short)(u >> 16);
}
// monotone map: f32 order == unsigned order of (f2sort32(f)>>16).
__device__ __forceinline__ unsigned f2sort32(float f) {
    unsigned u = __float_as_uint(f);
    u += 0x7FFFu + ((u >> 16) & 1u);               // RNE to bf16 in high half
    return u ^ (0x80000000u | (unsigned)((int)u >> 31));
}
__device__ __forceinline__ float sort2f(unsigned int y) {
    unsigned int x = (y & 0x8000u) ? (y ^ 0x8000u) : (~y & 0xFFFFu);
    return __uint_as_float(x << 16);
}
__device__ __forceinline__ unsigned umax(unsigned a, unsigned b) { return a > b ? a : b; }
__device__ __forceinline__ unsigned umin(unsigned a, unsigned b) { return a < b ? a : b; }

__device__ __forceinline__ void gload_lds16(const void* g, void* l) {
    __builtin_amdgcn_global_load_lds(
        (const __attribute__((address_space(1))) unsigned int*)(uintptr_t)g,
        (__attribute__((address_space(3))) unsigned int*)(uintptr_t)l,
        16, 0, 0);
}

// ---- zero the 3 scalar accumulators -----------------------------------------
__global__ void zero_scalars(float* sc) {
    if (threadIdx.x < 3) sc[threadIdx.x] = 0.0f;
}

// ---- fused f32->bf16 conversion (4 arrays) + dot(X,Y); grid.y selects ------
__global__ void prep_kernel(const float4* __restrict__ X,
                            const float4* __restrict__ Y,
                            const float4* __restrict__ Zt,
                            const float4* __restrict__ Ztr,
                            ushort4* __restrict__ A0, ushort4* __restrict__ A1,
                            ushort4* __restrict__ B0, ushort4* __restrict__ B1,
                            float* __restrict__ dotacc) {
    const int z = blockIdx.y;
    int i = blockIdx.x * 256 + threadIdx.x;
    const int stride = gridDim.x * 256;
    if (z == 0) {
        float s = 0.0f;
        for (; i < B_ROWS * D_K / 4; i += stride) {
            float4 x = X[i], y = Y[i];
            ushort4 u; u.x = f2bf(x.x); u.y = f2bf(x.y);
            u.z = f2bf(x.z); u.w = f2bf(x.w);
            A0[i] = u;
            s += x.x * y.x + x.y * y.y + x.z * y.z + x.w * y.w;
        }
        for (int o = 32; o > 0; o >>= 1) s += __shfl_down(s, o);
        __shared__ float wsum[4];
        int lane = threadIdx.x & 63, w = threadIdx.x >> 6;
        if (lane == 0) wsum[w] = s;
        __syncthreads();
        if (threadIdx.x == 0)
            atomicAdd(dotacc, wsum[0] + wsum[1] + wsum[2] + wsum[3]);
    } else {
        const float4* src = (z == 1) ? Y : (z == 2) ? Zt : Ztr;
        ushort4* dst = (z == 1) ? A1 : (z == 2) ? B0 : B1;
        int n4 = (z == 1) ? (B_ROWS * D_K / 4) : (N_COLS * D_K / 4);
        for (; i < n4; i += stride) {
            float4 f = src[i];
            ushort4 u; u.x = f2bf(f.x); u.y = f2bf(f.y);
            u.z = f2bf(f.z); u.w = f2bf(f.w);
            dst[i] = u;
        }
    }
}

// ---- pipeline / epilogue macros --------------------------------------------
#define BARRIER()  asm volatile("s_barrier" ::: "memory")
#define VMCNT(N)   asm volatile("s_waitcnt vmcnt(" #N ")" ::: "memory")
#define LGKM0()    asm volatile("s_waitcnt lgkmcnt(0)" ::: "memory")

// stage sub-tile T (K cols [T*32, T*32+32)) into slot T&3.
// wave w stages A rows [w*32, w*32+32) and B cols likewise; lane order ==
// fragment order (conflict-free by construction; LDS dest is wave-uniform).
#define STAGE(T) do { \
    gload_lds16(gA + (T) * 32,      smem + ((T) & 3) * 16384 + (w * 2 + 0) * 512); \
    gload_lds16(gA + (T) * 32 + 16, smem + ((T) & 3) * 16384 + (w * 2 + 1) * 512); \
    gload_lds16(gB + (T) * 32,      smem + ((T) & 3) * 16384 + 8192 + (w * 2 + 0) * 512); \
    gload_lds16(gB + (T) * 32 + 16, smem + ((T) & 3) * 16384 + 8192 + (w * 2 + 1) * 512); \
} while (0)

// load one half-KSTEP's fragments (4 A frags + 2 B frags) from slot/kk
#define LOADH(AF, BF, SLOT, KK) { \
    _Pragma("unroll") for (int rb = 0; rb < 4; ++rb) \
        AF[rb] = *(const bf16x8*)(smem + (SLOT) * 16384 + ((wm * 4 + rb) * 2 + (KK)) * 512 + lane8); \
    _Pragma("unroll") for (int cb = 0; cb < 2; ++cb) \
        BF[cb] = *(const bf16x8*)(smem + (SLOT) * 16384 + 8192 + ((wn * 2 + cb) * 2 + (KK)) * 512 + lane8); \
}

// 8 MFMAs: acc[rb][cb] += BF[cb] (M=cols) x AF[rb] (N=rows)
#define MFMAH(AF, BF) { \
    _Pragma("unroll") for (int rb = 0; rb < 4; ++rb) { \
    _Pragma("unroll") for (int cb = 0; cb < 2; ++cb) { \
        acc[rb][cb] = __builtin_amdgcn_mfma_f32_32x32x16_bf16( \
            BF[cb], AF[rb], acc[rb][cb], 0, 0, 0); } } }

#define KSTEP(J) do { \
    LOADH(afn, bfn, (J) & 3, 1); \
    MFMAH(afc, bfc); \
    if ((J) < 15) LOADH(afc, bfc, ((J) + 1) & 3, 0); \
    MFMAH(afn, bfn); \
    if ((J) < 12)       { LGKM0(); VMCNT(4); BARRIER(); STAGE((J) + 4); } \
    else if ((J) == 12) { VMCNT(4); BARRIER(); } \
    else if ((J) == 13) { VMCNT(0); BARRIER(); } \
} while (0)

#define CSWAP(a, b) { unsigned _hi = umax(a, b), _lo = umin(a, b); a = _hi; b = _lo; }
#define SORT4() { CSWAP(m0, m1); CSWAP(m2, m3); CSWAP(m0, m2); CSWAP(m1, m3); CSWAP(m1, m2); }
#define INS(V) { u16x2 _hi; \
    _hi = __builtin_elementwise_max(t0, V); V = __builtin_elementwise_min(t0, V); t0 = _hi; \
    _hi = __builtin_elementwise_max(t1, V); V = __builtin_elementwise_min(t1, V); t1 = _hi; \
    _hi = __builtin_elementwise_max(t2, V); V = __builtin_elementwise_min(t2, V); t2 = _hi; \
    _hi = __builtin_elementwise_max(t3, V); V = __builtin_elementwise_min(t3, V); t3 = _hi; }

// ---- 256x256 bf16 GEMM (32x32x16 MFMA) + in-register per-(row,64col) top-4 -
// grid (2048, 2): y selects which GEMM. 512 threads = 8 waves (2M x 4N).
__global__ __launch_bounds__(512, 2)
void gemm_topk_kernel(const unsigned short* __restrict__ A0g,
                      const unsigned short* __restrict__ A1g,
                      const unsigned short* __restrict__ B0g,
                      const unsigned short* __restrict__ B1g,
                      uint2* __restrict__ P0, uint2* __restrict__ P1) {
    const unsigned short* A  = blockIdx.y ? A1g : A0g;
    const unsigned short* Bm = blockIdx.y ? B1g : B0g;
    uint2* P2 = blockIdx.y ? P1 : P0;

    __shared__ __align__(128) unsigned short smem[4 * 16384];  // 128 KiB

    const int tid   = threadIdx.x;
    const int lane  = tid & 63;
    const int w     = tid >> 6;       // wave 0..7
    const int wm    = w >> 2;         // 0..1 : 128-row half
    const int wn    = w & 3;          // 0..3 : 64-col window
    const int rlane = lane & 31;
    const int hi    = lane >> 5;
    const int lane8 = lane * 8;

    // XCD swizzle: xcd owns a 16-col-block window; 8-block group stays in L2
    const int b      = blockIdx.x;
    const int xcd    = b & 7;
    const int ii     = b >> 3;            // 0..255
    const int cw     = ii & 7;
    const int rowblk = (ii >> 3) & 15;
    const int cg     = ii >> 7;           // 0..1
    const int bn     = xcd * 16 + cg * 8 + cw;   // 0..127
    const int row0   = rowblk * 256;
    const int col0   = bn * 256;

    // staging sources: wave w owns A block row0+w*32.., B block col0+w*32..;
    // lane (hi,rlane) -> row +rlane, k-offset hi*8  (fragment lane order)
    const unsigned short* gA = A  + (size_t)(row0 + w * 32 + rlane) * D_K + hi * 8;
    const unsigned short* gB = Bm + (size_t)(col0 + w * 32 + rlane) * D_K + hi * 8;

    f32x16 acc[4][2];
    #pragma unroll
    for (int rb = 0; rb < 4; ++rb)
        #pragma unroll
        for (int cb = 0; cb < 2; ++cb)
            #pragma unroll
            for (int e = 0; e < 16; ++e)
                acc[rb][cb][e] = 0.0f;

    bf16x8 afc[4], afn[4], bfc[2], bfn[2];

    // ---- prologue ----
    STAGE(0);
    STAGE(1);
    STAGE(2);
    STAGE(3);
    VMCNT(8);        // S0, S1 landed (per wave)
    BARRIER();       // publish S0, S1
    LOADH(afc, bfc, 0, 0)

    // ---- main loop: 16 K sub-tiles ----
    KSTEP(0);  KSTEP(1);  KSTEP(2);  KSTEP(3);
    KSTEP(4);  KSTEP(5);  KSTEP(6);  KSTEP(7);
    KSTEP(8);  KSTEP(9);  KSTEP(10); KSTEP(11);
    KSTEP(12); KSTEP(13); KSTEP(14); KSTEP(15);

    // ---- epilogue: per-row top-4 of this wave's 64-col window, in regs ----
    // 32x32 swapped C layout: X-row = rlane (fixed/lane); col-within-block =
    // (reg&3) + 8*(reg>>2) + 4*hi.  Lane holds 16 cols of each of the 2
    // col-blocks = 32 of the window's 64; partner lane^32 holds the rest.
    const int chunk = bn * 2 + (wn >> 1);
    const int half  = wn & 1;
    #pragma unroll
    for (int rb = 0; rb < 4; ++rb) {
        u16x2 t0 = {0, 0}, t1 = {0, 0}, t2 = {0, 0}, t3 = {0, 0};
        #pragma unroll
        for (int cb = 0; cb < 2; ++cb) {
            #pragma unroll
            for (int p = 0; p < 8; ++p) {
                unsigned sa = f2sort32(acc[rb][cb][2 * p]);
                unsigned sb = f2sort32(acc[rb][cb][2 * p + 1]);
                unsigned pk = (sa >> 16) | (sb & 0xFFFF0000u);
                u16x2 v = *(u16x2*)&pk;
                INS(v);
            }
        }
        // top-4 multiset of this lane's 32 values (chains sorted desc)
        unsigned m0 = umax((unsigned)t0.x, (unsigned)t3.y);
        unsigned m1 = umax((unsigned)t1.x, (unsigned)t2.y);
        unsigned m2 = umax((unsigned)t2.x, (unsigned)t1.y);
        unsigned m3 = umax((unsigned)t3.x, (unsigned)t0.y);
        SORT4();
        // single bitonic merge with lane^32 (partner holds the other 32 cols)
        {
            unsigned pa = m0 | (m1 << 16);
            unsigned pb = m2 | (m3 << 16);
            unsigned qa = (unsigned)__shfl_xor((int)pa, 32);
            unsigned qb = (unsigned)__shfl_xor((int)pb, 32);
            unsigned ra = (qa >> 16) | (qa << 16);   // (q1, q0)
            unsigned rb2 = (qb >> 16) | (qb << 16);  // (q3, q2)
            u16x2 n0 = __builtin_elementwise_max(*(u16x2*)&pa, *(u16x2*)&rb2);
            u16x2 n1 = __builtin_elementwise_max(*(u16x2*)&pb, *(u16x2*)&ra);
            m0 = n0.x; m1 = n0.y; m2 = n1.x; m3 = n1.y;
            SORT4();
        }
        if (hi == 0) {
            int row_g = row0 + wm * 128 + rb * 32 + rlane;
            P2[((size_t)row_g * NCHUNK + chunk) * 2 + half] =
                make_uint2(m0 | (m1 << 16), m2 | (m3 << 16));
        }
    }
}

// ---- per-row exact top-10 over 2048 u16 candidates; one wave per row --------
// grid (1024, 2): y selects which GEMM's P / accumulator.  (unchanged)
__global__ __launch_bounds__(256, 4)
void merge_topk_kernel(const unsigned int* __restrict__ P0,
                       const unsigned int* __restrict__ P1,
                       float* __restrict__ sc) {
    const int g    = blockIdx.y;
    const int lane = threadIdx.x & 63;
    const int w    = threadIdx.x >> 6;
    const int row  = blockIdx.x * 4 + w;
    const unsigned int* Rp = (g ? P1 : P0) + (size_t)row * (NCHUNK * 4); // 1024 u32

    u16x2 t[10];
    #pragma unroll
    for (int i = 0; i < 10; ++i) t[i] = (u16x2){0, 0};
    #pragma unroll 4
    for (int it = 0; it < 16; ++it) {
        unsigned int raw = Rp[lane + 64 * it];
        u16x2 v = *(u16x2*)&raw;
        #pragma unroll
        for (int i = 0; i < 10; ++i) {
            u16x2 hi = __builtin_elementwise_max(t[i], v);
            v = __builtin_elementwise_min(t[i], v);
            t[i] = hi;
        }
    }
    unsigned int wreg[10];
    #pragma unroll
    for (int i = 0; i < 10; ++i) {
        unsigned int mv = umax((unsigned int)t[i].x,
                               (unsigned int)t[9 - i].y);
        wreg[i] = (mv << 16) | ((unsigned int)lane << 4) | (unsigned int)i;
    }
    float sum10 = 0.0f;
    #pragma unroll
    for (int iter = 0; iter < 10; ++iter) {
        unsigned int mx = wreg[0];
        #pragma unroll
        for (int s = 1; s < 10; ++s) mx = umax(mx, wreg[s]);
        #pragma unroll
        for (int o = 32; o > 0; o >>= 1)
            mx = umax(mx, (unsigned int)__shfl_xor((int)mx, o));
        sum10 += sort2f(mx >> 16);
        #pragma unroll
        for (int s = 0; s < 10; ++s)
            if (wreg[s] == mx) wreg[s] = 0u;
    }
    if (lane == 0) atomicAdd(sc + 1 + g, sum10);
}

// ---- final scalar -----------------------------------------------------------
__global__ void finalize_kernel(const float* __restrict__ sc,
                                float* __restrict__ out) {
    if (threadIdx.x == 0) {
        float f = (sc[1] * 0.1f + sc[2] * 0.1f - 2.0f * sc[0]) * (1.0f / 4096.0f);
        out[0] = f;
    }
}

extern "C" void kernel_launch(void* const* d_in, const int* in_sizes, int n_in,
                              void* d_out, int out_size, void* d_ws, size_t ws_size,
                              hipStream_t stream) {
    const float* X_trans = (const float*)d_in[1];
    const float* Y_tgt   = (const float*)d_in[2];
    const float* Z_trans = (const float*)d_in[4];
    const float* Z_tgt   = (const float*)d_in[5];

    char* ws = (char*)d_ws;
    float* sc = (float*)ws;                                  // [0]=dot [1]=fk0 [2]=fk1
    unsigned short* A0 = (unsigned short*)(ws + 256);        // X_trans bf16 [4096,512]
    unsigned short* A1 = A0 + (size_t)B_ROWS * D_K;          // Y_tgt  bf16
    unsigned short* B0 = A1 + (size_t)B_ROWS * D_K;          // Z_tgt  bf16 [32768,512]
    unsigned short* B1 = B0 + (size_t)N_COLS * D_K;          // Z_trans bf16
    uint2* P0 = (uint2*)(B1 + (size_t)N_COLS * D_K);         // [4096][256][2] uint2
    uint2* P1 = P0 + (size_t)B_ROWS * NCHUNK * 2;

    zero_scalars<<<1, 64, 0, stream>>>(sc);

    dim3 pgrid(2048, 4);
    prep_kernel<<<pgrid, 256, 0, stream>>>(
        (const float4*)X_trans, (const float4*)Y_tgt,
        (const float4*)Z_tgt, (const float4*)Z_trans,
        (ushort4*)A0, (ushort4*)A1, (ushort4*)B0, (ushort4*)B1, sc + 0);

    dim3 ggrid(2048, 2);
    gemm_topk_kernel<<<ggrid, 512, 0, stream>>>(A0, A1, B0, B1, P0, P1);

    dim3 mgrid(B_ROWS / 4, 2);
    merge_topk_kernel<<<mgrid, 256, 0, stream>>>(
        (const unsigned int*)P0, (const unsigned int*)P1, sc);

    finalize_kernel<<<1, 64, 0, stream>>>(sc, (float*)d_out);
}

// Round 5
// 692.012 us; speedup vs baseline: 1.0048x; 1.0006x over previous
//
#include <hip/hip_runtime.h>
#include <hip/hip_bf16.h>
#include <float.h>
#include <cstdint>

// ---------------------------------------------------------------------------
// RCSLS: out = ( topk10sum(X_trans@Z_tgt^T)/10 + topk10sum(Y_tgt@Z_trans^T)/10
//               - 2*sum(X_trans*Y_tgt) ) / 4096
// B=4096, N=32768, d=512, k=10.  Inputs f32; GEMMs in bf16 MFMA.
//
// R9: 8-phase-style schedule (m201 template) on the R8 geometry.
// R5/R7/R8 post-mortem: three different K-loop micro-schedules all ~3600
// cyc/KSTEP -> the limiter is the 2-phase sync structure itself (m233: 72%
// stage+vmcnt+barrier overhead), not intra-KSTEP scheduling.  The measured
// fix is the phase discipline: small per-phase read batch + gload issue,
// barrier, lgkmcnt(0), setprio'd MFMA cluster, barrier; vmcnt counted once
// per sub-tile and never drained to 0 in steady state (T3+T4), setprio
// pays only with this phase split (T5, m218b).
//
// Geometry (unchanged from R8): 256x256 tile, 8 waves (2M x 4N), MFMA
// 32x32x16, 16 K sub-tiles of 32 through a 4-slot (4 x 32KB) LDS rotation,
// fragment-order LDS (conflict-free both sides: measured 0 bank conflicts —
// provides what m201's st_16x32 swizzle provides).
//
// Per K32 sub-tile J (2 phases):
//  PhA: LOADH(slot J&3, kk0) [6 ds_read_b128] | STAGE_A(J+3) [2 gloads]
//       BAR ; lgkm0 ; setprio1 ; 8 MFMA ; setprio0 ; BAR
//  PhB: LOADH(slot J&3, kk1) | STAGE_B(J+3) [2 gloads]
//       BAR ; lgkm0 ; setprio1 ; 8 MFMA ; setprio0 ;
//       VMCNT(8 | 4@J13 | 0@J14) ; BAR
// Ledger: S(J+3) issued during subtile J (2+2 gloads).  End-of-PhB vmcnt(8)
// gates S(J+1) landed (allows S(J+2)+S(J+3)=8 in flight); barrier then
// publishes cross-wave.  WAR: slot (J+3)&3's last reads (PhB(J-1) kk1) are
// drained by PhB(J-1)'s lgkm0 before its closing barrier, which precedes
// PhA(J)'s STAGE_A(J+3).  Prologue stages S0..S2, vmcnt(8) [S0 landed],
// barrier.  Tail: no stage for J>=13; vmcnt 4 @J=13, 0 @J=14.
//
// Swapped MFMA operands (mfma(b_frag, a_frag)): lane&31 = X-row, so the
// per-(row, 64-col-window) top-4 runs in registers: packed-u16 insertion
// network + ONE shfl_xor(32) bitonic merge.  P layout & merge kernel
// unchanged; sortable-u16 mapping bit-identical to previous versions.
// ---------------------------------------------------------------------------

#define B_ROWS 4096
#define N_COLS 32768
#define D_K    512
#define NCHUNK (N_COLS / 128)   // 256 chunks of 128 cols (P layout, unchanged)

typedef __bf16 bf16x8 __attribute__((ext_vector_type(8)));
typedef float  f32x16 __attribute__((ext_vector_type(16)));
typedef unsigned short u16x2 __attribute__((ext_vector_type(2)));

__device__ __forceinline__ unsigned short f2bf(float f) {
    unsigned int u = __float_as_uint(f);
    u += 0x7FFFu + ((u >> 16) & 1u);   // RNE
    return (unsigned short)(u >> 16);
}
// monotone map: f32 order == unsigned order of (f2sort32(f)>>16).
__device__ __forceinline__ unsigned f2sort32(float f) {
    unsigned u = __float_as_uint(f);
    u += 0x7FFFu + ((u >> 16) & 1u);               // RNE to bf16 in high half
    return u ^ (0x80000000u | (unsigned)((int)u >> 31));
}
__device__ __forceinline__ float sort2f(unsigned int y) {
    unsigned int x = (y & 0x8000u) ? (y ^ 0x8000u) : (~y & 0xFFFFu);
    return __uint_as_float(x << 16);
}
__device__ __forceinline__ unsigned umax(unsigned a, unsigned b) { return a > b ? a : b; }
__device__ __forceinline__ unsigned umin(unsigned a, unsigned b) { return a < b ? a : b; }

__device__ __forceinline__ void gload_lds16(const void* g, void* l) {
    __builtin_amdgcn_global_load_lds(
        (const __attribute__((address_space(1))) unsigned int*)(uintptr_t)g,
        (__attribute__((address_space(3))) unsigned int*)(uintptr_t)l,
        16, 0, 0);
}

// ---- zero the 3 scalar accumulators -----------------------------------------
__global__ void zero_scalars(float* sc) {
    if (threadIdx.x < 3) sc[threadIdx.x] = 0.0f;
}

// ---- fused f32->bf16 conversion (4 arrays) + dot(X,Y); grid.y selects ------
__global__ void prep_kernel(const float4* __restrict__ X,
                            const float4* __restrict__ Y,
                            const float4* __restrict__ Zt,
                            const float4* __restrict__ Ztr,
                            ushort4* __restrict__ A0, ushort4* __restrict__ A1,
                            ushort4* __restrict__ B0, ushort4* __restrict__ B1,
                            float* __restrict__ dotacc) {
    const int z = blockIdx.y;
    int i = blockIdx.x * 256 + threadIdx.x;
    const int stride = gridDim.x * 256;
    if (z == 0) {
        float s = 0.0f;
        for (; i < B_ROWS * D_K / 4; i += stride) {
            float4 x = X[i], y = Y[i];
            ushort4 u; u.x = f2bf(x.x); u.y = f2bf(x.y);
            u.z = f2bf(x.z); u.w = f2bf(x.w);
            A0[i] = u;
            s += x.x * y.x + x.y * y.y + x.z * y.z + x.w * y.w;
        }
        for (int o = 32; o > 0; o >>= 1) s += __shfl_down(s, o);
        __shared__ float wsum[4];
        int lane = threadIdx.x & 63, w = threadIdx.x >> 6;
        if (lane == 0) wsum[w] = s;
        __syncthreads();
        if (threadIdx.x == 0)
            atomicAdd(dotacc, wsum[0] + wsum[1] + wsum[2] + wsum[3]);
    } else {
        const float4* src = (z == 1) ? Y : (z == 2) ? Zt : Ztr;
        ushort4* dst = (z == 1) ? A1 : (z == 2) ? B0 : B1;
        int n4 = (z == 1) ? (B_ROWS * D_K / 4) : (N_COLS * D_K / 4);
        for (; i < n4; i += stride) {
            float4 f = src[i];
            ushort4 u; u.x = f2bf(f.x); u.y = f2bf(f.y);
            u.z = f2bf(f.z); u.w = f2bf(f.w);
            dst[i] = u;
        }
    }
}

// ---- pipeline / epilogue macros --------------------------------------------
#define BARRIER()  asm volatile("s_barrier" ::: "memory")
#define VMCNT(N)   asm volatile("s_waitcnt vmcnt(" #N ")" ::: "memory")
#define LGKM0()    asm volatile("s_waitcnt lgkmcnt(0)" ::: "memory")

// stage A / B half of sub-tile T (K cols [T*32, T*32+32)) into slot T&3.
// wave w stages its own 32 rows/cols; lane order == fragment order
// (conflict-free; LDS dest is wave-uniform + lane*16B).  Compile-time
// guard skips nonexistent tiles in the tail.
#define STAGE_A(T) do { if ((T) <= 15) { \
    gload_lds16(gA + (T) * 32,      smem + ((T) & 3) * 16384 + (w * 2 + 0) * 512); \
    gload_lds16(gA + (T) * 32 + 16, smem + ((T) & 3) * 16384 + (w * 2 + 1) * 512); } \
} while (0)
#define STAGE_B(T) do { if ((T) <= 15) { \
    gload_lds16(gB + (T) * 32,      smem + ((T) & 3) * 16384 + 8192 + (w * 2 + 0) * 512); \
    gload_lds16(gB + (T) * 32 + 16, smem + ((T) & 3) * 16384 + 8192 + (w * 2 + 1) * 512); } \
} while (0)

// load one phase's fragments (4 A frags + 2 B frags) from slot/kk
#define LOADH(AF, BF, SLOT, KK) { \
    _Pragma("unroll") for (int rb = 0; rb < 4; ++rb) \
        AF[rb] = *(const bf16x8*)(smem + (SLOT) * 16384 + ((wm * 4 + rb) * 2 + (KK)) * 512 + lane8); \
    _Pragma("unroll") for (int cb = 0; cb < 2; ++cb) \
        BF[cb] = *(const bf16x8*)(smem + (SLOT) * 16384 + 8192 + ((wn * 2 + cb) * 2 + (KK)) * 512 + lane8); \
}

// 8 MFMAs: acc[rb][cb] += BF[cb] (M=cols) x AF[rb] (N=rows)
#define MFMAH(AF, BF) { \
    _Pragma("unroll") for (int rb = 0; rb < 4; ++rb) { \
    _Pragma("unroll") for (int cb = 0; cb < 2; ++cb) { \
        acc[rb][cb] = __builtin_amdgcn_mfma_f32_32x32x16_bf16( \
            BF[cb], AF[rb], acc[rb][cb], 0, 0, 0); } } }

// one K32 sub-tile = two phases (kk0, kk1), m201 discipline
#define KSTEP(J) do { \
    /* phase A */ \
    LOADH(afc, bfc, (J) & 3, 0); \
    STAGE_A((J) + 3); \
    BARRIER(); \
    LGKM0(); \
    __builtin_amdgcn_s_setprio(1); \
    MFMAH(afc, bfc); \
    __builtin_amdgcn_s_setprio(0); \
    BARRIER(); \
    /* phase B */ \
    LOADH(afn, bfn, (J) & 3, 1); \
    STAGE_B((J) + 3); \
    BARRIER(); \
    LGKM0(); \
    __builtin_amdgcn_s_setprio(1); \
    MFMAH(afn, bfn); \
    __builtin_amdgcn_s_setprio(0); \
    if ((J) <= 12)      { VMCNT(8); } \
    else if ((J) == 13) { VMCNT(4); } \
    else if ((J) == 14) { VMCNT(0); } \
    BARRIER(); \
} while (0)

#define CSWAP(a, b) { unsigned _hi = umax(a, b), _lo = umin(a, b); a = _hi; b = _lo; }
#define SORT4() { CSWAP(m0, m1); CSWAP(m2, m3); CSWAP(m0, m2); CSWAP(m1, m3); CSWAP(m1, m2); }
#define INS(V) { u16x2 _hi; \
    _hi = __builtin_elementwise_max(t0, V); V = __builtin_elementwise_min(t0, V); t0 = _hi; \
    _hi = __builtin_elementwise_max(t1, V); V = __builtin_elementwise_min(t1, V); t1 = _hi; \
    _hi = __builtin_elementwise_max(t2, V); V = __builtin_elementwise_min(t2, V); t2 = _hi; \
    _hi = __builtin_elementwise_max(t3, V); V = __builtin_elementwise_min(t3, V); t3 = _hi; }

// ---- 256x256 bf16 GEMM (32x32x16 MFMA) + in-register per-(row,64col) top-4 -
// grid (2048, 2): y selects which GEMM. 512 threads = 8 waves (2M x 4N).
__global__ __launch_bounds__(512, 2)
void gemm_topk_kernel(const unsigned short* __restrict__ A0g,
                      const unsigned short* __restrict__ A1g,
                      const unsigned short* __restrict__ B0g,
                      const unsigned short* __restrict__ B1g,
                      uint2* __restrict__ P0, uint2* __restrict__ P1) {
    const unsigned short* A  = blockIdx.y ? A1g : A0g;
    const unsigned short* Bm = blockIdx.y ? B1g : B0g;
    uint2* P2 = blockIdx.y ? P1 : P0;

    __shared__ __align__(128) unsigned short smem[4 * 16384];  // 128 KiB

    const int tid   = threadIdx.x;
    const int lane  = tid & 63;
    const int w     = tid >> 6;       // wave 0..7
    const int wm    = w >> 2;         // 0..1 : 128-row half
    const int wn    = w & 3;          // 0..3 : 64-col window
    const int rlane = lane & 31;
    const int hi    = lane >> 5;
    const int lane8 = lane * 8;

    // XCD swizzle: xcd owns a 16-col-block window; 8-block group stays in L2
    const int b      = blockIdx.x;
    const int xcd    = b & 7;
    const int ii     = b >> 3;            // 0..255
    const int cw     = ii & 7;
    const int rowblk = (ii >> 3) & 15;
    const int cg     = ii >> 7;           // 0..1
    const int bn     = xcd * 16 + cg * 8 + cw;   // 0..127
    const int row0   = rowblk * 256;
    const int col0   = bn * 256;

    // staging sources: wave w owns A block row0+w*32.., B block col0+w*32..;
    // lane (hi,rlane) -> row +rlane, k-offset hi*8  (fragment lane order)
    const unsigned short* gA = A  + (size_t)(row0 + w * 32 + rlane) * D_K + hi * 8;
    const unsigned short* gB = Bm + (size_t)(col0 + w * 32 + rlane) * D_K + hi * 8;

    f32x16 acc[4][2];
    #pragma unroll
    for (int rb = 0; rb < 4; ++rb)
        #pragma unroll
        for (int cb = 0; cb < 2; ++cb)
            #pragma unroll
            for (int e = 0; e < 16; ++e)
                acc[rb][cb][e] = 0.0f;

    bf16x8 afc[4], afn[4], bfc[2], bfn[2];

    // ---- prologue: stage S0..S2 (12 gloads), gate S0, publish ----
    STAGE_A(0); STAGE_B(0);
    STAGE_A(1); STAGE_B(1);
    STAGE_A(2); STAGE_B(2);
    VMCNT(8);        // S0 landed (S1,S2 may be in flight)
    BARRIER();       // publish S0

    // ---- main loop: 16 K sub-tiles x 2 phases ----
    KSTEP(0);  KSTEP(1);  KSTEP(2);  KSTEP(3);
    KSTEP(4);  KSTEP(5);  KSTEP(6);  KSTEP(7);
    KSTEP(8);  KSTEP(9);  KSTEP(10); KSTEP(11);
    KSTEP(12); KSTEP(13); KSTEP(14); KSTEP(15);

    // ---- epilogue: per-row top-4 of this wave's 64-col window, in regs ----
    // 32x32 swapped C layout: X-row = rlane (fixed/lane); col-within-block =
    // (reg&3) + 8*(reg>>2) + 4*hi.  Lane holds 16 cols of each of the 2
    // col-blocks = 32 of the window's 64; partner lane^32 holds the rest.
    const int chunk = bn * 2 + (wn >> 1);
    const int half  = wn & 1;
    #pragma unroll
    for (int rb = 0; rb < 4; ++rb) {
        u16x2 t0 = {0, 0}, t1 = {0, 0}, t2 = {0, 0}, t3 = {0, 0};
        #pragma unroll
        for (int cb = 0; cb < 2; ++cb) {
            #pragma unroll
            for (int p = 0; p < 8; ++p) {
                unsigned sa = f2sort32(acc[rb][cb][2 * p]);
                unsigned sb = f2sort32(acc[rb][cb][2 * p + 1]);
                unsigned pk = (sa >> 16) | (sb & 0xFFFF0000u);
                u16x2 v = *(u16x2*)&pk;
                INS(v);
            }
        }
        // top-4 multiset of this lane's 32 values (chains sorted desc)
        unsigned m0 = umax((unsigned)t0.x, (unsigned)t3.y);
        unsigned m1 = umax((unsigned)t1.x, (unsigned)t2.y);
        unsigned m2 = umax((unsigned)t2.x, (unsigned)t1.y);
        unsigned m3 = umax((unsigned)t3.x, (unsigned)t0.y);
        SORT4();
        // single bitonic merge with lane^32 (partner holds the other 32 cols)
        {
            unsigned pa = m0 | (m1 << 16);
            unsigned pb = m2 | (m3 << 16);
            unsigned qa = (unsigned)__shfl_xor((int)pa, 32);
            unsigned qb = (unsigned)__shfl_xor((int)pb, 32);
            unsigned ra = (qa >> 16) | (qa << 16);   // (q1, q0)
            unsigned rb2 = (qb >> 16) | (qb << 16);  // (q3, q2)
            u16x2 n0 = __builtin_elementwise_max(*(u16x2*)&pa, *(u16x2*)&rb2);
            u16x2 n1 = __builtin_elementwise_max(*(u16x2*)&pb, *(u16x2*)&ra);
            m0 = n0.x; m1 = n0.y; m2 = n1.x; m3 = n1.y;
            SORT4();
        }
        if (hi == 0) {
            int row_g = row0 + wm * 128 + rb * 32 + rlane;
            P2[((size_t)row_g * NCHUNK + chunk) * 2 + half] =
                make_uint2(m0 | (m1 << 16), m2 | (m3 << 16));
        }
    }
}

// ---- per-row exact top-10 over 2048 u16 candidates; one wave per row --------
// grid (1024, 2): y selects which GEMM's P / accumulator.  (unchanged)
__global__ __launch_bounds__(256, 4)
void merge_topk_kernel(const unsigned int* __restrict__ P0,
                       const unsigned int* __restrict__ P1,
                       float* __restrict__ sc) {
    const int g    = blockIdx.y;
    const int lane = threadIdx.x & 63;
    const int w    = threadIdx.x >> 6;
    const int row  = blockIdx.x * 4 + w;
    const unsigned int* Rp = (g ? P1 : P0) + (size_t)row * (NCHUNK * 4); // 1024 u32

    u16x2 t[10];
    #pragma unroll
    for (int i = 0; i < 10; ++i) t[i] = (u16x2){0, 0};
    #pragma unroll 4
    for (int it = 0; it < 16; ++it) {
        unsigned int raw = Rp[lane + 64 * it];
        u16x2 v = *(u16x2*)&raw;
        #pragma unroll
        for (int i = 0; i < 10; ++i) {
            u16x2 hi = __builtin_elementwise_max(t[i], v);
            v = __builtin_elementwise_min(t[i], v);
            t[i] = hi;
        }
    }
    unsigned int wreg[10];
    #pragma unroll
    for (int i = 0; i < 10; ++i) {
        unsigned int mv = umax((unsigned int)t[i].x,
                               (unsigned int)t[9 - i].y);
        wreg[i] = (mv << 16) | ((unsigned int)lane << 4) | (unsigned int)i;
    }
    float sum10 = 0.0f;
    #pragma unroll
    for (int iter = 0; iter < 10; ++iter) {
        unsigned int mx = wreg[0];
        #pragma unroll
        for (int s = 1; s < 10; ++s) mx = umax(mx, wreg[s]);
        #pragma unroll
        for (int o = 32; o > 0; o >>= 1)
            mx = umax(mx, (unsigned int)__shfl_xor((int)mx, o));
        sum10 += sort2f(mx >> 16);
        #pragma unroll
        for (int s = 0; s < 10; ++s)
            if (wreg[s] == mx) wreg[s] = 0u;
    }
    if (lane == 0) atomicAdd(sc + 1 + g, sum10);
}

// ---- final scalar -----------------------------------------------------------
__global__ void finalize_kernel(const float* __restrict__ sc,
                                float* __restrict__ out) {
    if (threadIdx.x == 0) {
        float f = (sc[1] * 0.1f + sc[2] * 0.1f - 2.0f * sc[0]) * (1.0f / 4096.0f);
        out[0] = f;
    }
}

extern "C" void kernel_launch(void* const* d_in, const int* in_sizes, int n_in,
                              void* d_out, int out_size, void* d_ws, size_t ws_size,
                              hipStream_t stream) {
    const float* X_trans = (const float*)d_in[1];
    const float* Y_tgt   = (const float*)d_in[2];
    const float* Z_trans = (const float*)d_in[4];
    const float* Z_tgt   = (const float*)d_in[5];

    char* ws = (char*)d_ws;
    float* sc = (float*)ws;                                  // [0]=dot [1]=fk0 [2]=fk1
    unsigned short* A0 = (unsigned short*)(ws + 256);        // X_trans bf16 [4096,512]
    unsigned short* A1 = A0 + (size_t)B_ROWS * D_K;          // Y_tgt  bf16
    unsigned short* B0 = A1 + (size_t)B_ROWS * D_K;          // Z_tgt  bf16 [32768,512]
    unsigned short* B1 = B0 + (size_t)N_COLS * D_K;          // Z_trans bf16
    uint2* P0 = (uint2*)(B1 + (size_t)N_COLS * D_K);         // [4096][256][2] uint2
    uint2* P1 = P0 + (size_t)B_ROWS * NCHUNK * 2;

    zero_scalars<<<1, 64, 0, stream>>>(sc);

    dim3 pgrid(2048, 4);
    prep_kernel<<<pgrid, 256, 0, stream>>>(
        (const float4*)X_trans, (const float4*)Y_tgt,
        (const float4*)Z_tgt, (const float4*)Z_trans,
        (ushort4*)A0, (ushort4*)A1, (ushort4*)B0, (ushort4*)B1, sc + 0);

    dim3 ggrid(2048, 2);
    gemm_topk_kernel<<<ggrid, 512, 0, stream>>>(A0, A1, B0, B1, P0, P1);

    dim3 mgrid(B_ROWS / 4, 2);
    merge_topk_kernel<<<mgrid, 256, 0, stream>>>(
        (const unsigned int*)P0, (const unsigned int*)P1, sc);

    finalize_kernel<<<1, 64, 0, stream>>>(sc, (float*)d_out);
}